// Round 3
// baseline (1128.288 us; speedup 1.0000x reference)
//
#include <hip/hip_runtime.h>
#include <hip/hip_bf16.h>

#define DD 384
#define NH 6
#define DHID 768

typedef __attribute__((ext_vector_type(8))) short bf16x8;
typedef __attribute__((ext_vector_type(4))) float f32x4;

__device__ __forceinline__ void gload_lds16(const void* gsrc, void* ldst) {
  __builtin_amdgcn_global_load_lds((const __attribute__((address_space(1))) void*)gsrc,
                                   (__attribute__((address_space(3))) void*)ldst,
                                   16, 0, 0);
}

union BPack { ushort4 u; __hip_bfloat16 b[4]; };

// ---------------- BatchNorm stats (+ fused bf16 cast of raw x) ----------------
__global__ __launch_bounds__(384) void bn_stats_k(const float* __restrict__ x, float* __restrict__ sums,
                                                  float* __restrict__ sq, __hip_bfloat16* __restrict__ xb,
                                                  int N, int rpb) {
  int d = threadIdx.x;
  int r0 = blockIdx.x * rpb;
  int r1 = min(r0 + rpb, N);
  float s = 0.f, ss = 0.f;
  for (int r = r0; r < r1; ++r) {
    size_t i = (size_t)r * DD + d;
    float v = x[i];
    s += v; ss += v * v;
    xb[i] = __float2bfloat16(v);
  }
  atomicAdd(&sums[d], s);
  atomicAdd(&sq[d], ss);
}

__global__ void bn_finalize_k(const float* sums, const float* sq, const float* g, const float* b,
                              float* a, float* c, int N) {
  int d = blockIdx.x * blockDim.x + threadIdx.x;
  if (d >= DD) return;
  float inv = 1.f / (float)N;
  float mu = sums[d] * inv;
  float var = sq[d] * inv - mu * mu;
  float rs = rsqrtf(var + 1e-5f);
  a[d] = rs * g[d];
  c[d] = b[d] - mu * rs * g[d];
}

// W' = bf16(diag(a) @ W), transposed to [Nout, K]; a == nullptr -> plain transpose
__global__ void transpose_scale_k(const float* __restrict__ in, const float* __restrict__ a,
                                  __hip_bfloat16* __restrict__ out, int K, int Nout) {
  int i = blockIdx.x * blockDim.x + threadIdx.x;
  if (i >= K * Nout) return;
  int k = i / Nout, n = i % Nout;
  float v = in[i];
  if (a) v *= a[k];
  out[(size_t)n * K + k] = __float2bfloat16(v);
}

// out[n] = bias[n] + sum_k c[k] * W[k][n]   (exact f32)
__global__ void bias_cw_k(const float* __restrict__ bias, const float* __restrict__ c,
                          const float* __restrict__ W, float* __restrict__ out, int K, int Nn) {
  int n = blockIdx.x * blockDim.x + threadIdx.x;
  if (n >= Nn) return;
  float s = bias ? bias[n] : 0.f;
  for (int k = 0; k < K; ++k) s += c[k] * W[(size_t)k * Nn + n];
  out[n] = s;
}

__global__ void f32_to_bf16_k(const float* __restrict__ in, __hip_bfloat16* __restrict__ out, int total4) {
  int i = blockIdx.x * blockDim.x + threadIdx.x;
  if (i >= total4) return;
  float4 v = ((const float4*)in)[i];
  BPack p;
  p.b[0] = __float2bfloat16(v.x);
  p.b[1] = __float2bfloat16(v.y);
  p.b[2] = __float2bfloat16(v.z);
  p.b[3] = __float2bfloat16(v.w);
  ((ushort4*)out)[i] = p.u;
}

// x1 = x + agg + skip, fused BN2 stats + fused bf16 cast of x1
__global__ __launch_bounds__(384) void add3_bn_k(const float* __restrict__ x, const float* __restrict__ agg,
                                                 const float* __restrict__ skip, float* __restrict__ x1,
                                                 __hip_bfloat16* __restrict__ xb1,
                                                 float* __restrict__ sums, float* __restrict__ sq,
                                                 int N, int rpb) {
  int d = threadIdx.x;
  int r0 = blockIdx.x * rpb;
  int r1 = min(r0 + rpb, N);
  float s = 0.f, ss = 0.f;
  for (int r = r0; r < r1; ++r) {
    size_t i = (size_t)r * DD + d;
    float v = x[i] + agg[i] + skip[i];
    x1[i] = v;
    xb1[i] = __float2bfloat16(v);
    s += v; ss += v * v;
  }
  atomicAdd(&sums[d], s);
  atomicAdd(&sq[d], ss);
}

// ---------------- CSR build ----------------
__global__ void hist_k(const int* __restrict__ ei, int* __restrict__ deg, int E) {
  int i = blockIdx.x * blockDim.x + threadIdx.x;
  if (i < E) atomicAdd(&deg[ei[E + i]], 1);
}

__global__ __launch_bounds__(1024) void scan_k(const int* __restrict__ deg, int* __restrict__ row_start,
                                               int* __restrict__ cursor, int N) {
  __shared__ int part[1024];
  int t = threadIdx.x;
  int ch = (N + 1023) / 1024;
  int c0 = t * ch, c1 = min(c0 + ch, N);
  int s = 0;
  for (int i = c0; i < c1; ++i) s += deg[i];
  part[t] = s;
  __syncthreads();
  for (int off = 1; off < 1024; off <<= 1) {
    int v = (t >= off) ? part[t - off] : 0;
    __syncthreads();
    part[t] += v;
    __syncthreads();
  }
  int run = part[t] - s;
  for (int i = c0; i < c1; ++i) {
    row_start[i] = run; cursor[i] = run; run += deg[i];
  }
  if (t == 1023) row_start[N] = part[1023];
}

__global__ void scatter_k(const int* __restrict__ ei, int* __restrict__ cursor,
                          int* __restrict__ csr_src, int* __restrict__ pos_of_eid, int E) {
  int i = blockIdx.x * blockDim.x + threadIdx.x;
  if (i >= E) return;
  int s = ei[i], d = ei[E + i];
  int pos = atomicAdd(&cursor[d], 1);
  csr_src[pos] = s;
  pos_of_eid[i] = pos;
}

// ---------------- attention (one wave per node; ebuf already in CSR order) ----------------
__global__ __launch_bounds__(256) void attn_k(const __hip_bfloat16* __restrict__ qkv,
                                              const __hip_bfloat16* __restrict__ ebuf,
                                              const int* __restrict__ row_start,
                                              const int* __restrict__ csr_src,
                                              float* __restrict__ agg, int N) {
  int wid = (blockIdx.x * blockDim.x + threadIdx.x) >> 6;
  int lane = threadIdx.x & 63;
  if (wid >= N) return;
  float q[NH], acc[NH], psum[NH];
#pragma unroll
  for (int h = 0; h < NH; ++h) {
    q[h] = __bfloat162float(qkv[(size_t)wid * 1152 + h * 64 + lane]);
    acc[h] = 0.f; psum[h] = 0.f;
  }
  int i0 = row_start[wid], i1 = row_start[wid + 1];
  for (int i = i0; i < i1; ++i) {
    int s = csr_src[i];
    size_t eb = (size_t)i * DD;
    size_t sb = (size_t)s * 1152;
    float ev[NH], p[NH];
#pragma unroll
    for (int h = 0; h < NH; ++h)
      ev[h] = __bfloat162float(ebuf[eb + h * 64 + lane]);
#pragma unroll
    for (int h = 0; h < NH; ++h) {
      float kk = __bfloat162float(qkv[sb + 384 + h * 64 + lane]);
      float t = q[h] * (kk + ev[h]);
#pragma unroll
      for (int off = 32; off > 0; off >>= 1) t += __shfl_xor(t, off);
      p[h] = expf(t * 0.125f);
    }
#pragma unroll
    for (int h = 0; h < NH; ++h) {
      float vv = __bfloat162float(qkv[sb + 768 + h * 64 + lane]) + ev[h];
      acc[h] += p[h] * vv;
      psum[h] += p[h];
    }
  }
#pragma unroll
  for (int h = 0; h < NH; ++h)
    agg[(size_t)wid * DD + h * 64 + lane] = psum[h] > 0.f ? acc[h] / psum[h] : 0.f;
}

// ---------------- GEMM (bf16 MFMA, 128x128 tile, BK=32, B pre-transposed) ----------------
// LDS layout XOR-swizzled (T2): data(row r, seg c) stored at 16B-unit  r*4 + (c ^ ((r>>1)&3)).
// global_load_lds writes linearly, so the swizzle is applied by permuting the SOURCE address
// per lane (rule #21) and un-permuting on the ds_read side.
#define BM 128
#define BN 128
#define BK 32

enum { M_QKVS = 0, M_BF16 = 1, M_GELU = 2, M_RES = 3 };

template <int MODE>
__global__ __launch_bounds__(256) void gemm_k(const __hip_bfloat16* __restrict__ A,
                                              const __hip_bfloat16* __restrict__ BT,
                                              const float* __restrict__ bias,
                                              const float* __restrict__ res,
                                              const int* __restrict__ perm,
                                              void* __restrict__ out0, void* __restrict__ out1,
                                              int M, int K, int Nn, int tn) {
  __shared__ short lA[BM * BK];
  __shared__ short lB[BN * BK];
  int t = threadIdx.x;
  int lane = t & 63, w = t >> 6;
  int wr = (w >> 1) * 64, wc = (w & 1) * 64;

  // bijective XCD-chunk swizzle, then column-fastest tile order (A-panel L2 reuse)
  int nwg = gridDim.x, bid = blockIdx.x;
  int q8 = nwg >> 3, r8 = nwg & 7;
  int xcd = bid & 7, lid = bid >> 3;
  int wgid = (xcd < r8 ? xcd * (q8 + 1) : r8 * (q8 + 1) + (xcd - r8) * q8) + lid;
  int bx = wgid / tn, by = wgid % tn;
  int row0 = bx * BM, col0 = by * BN;

  int lr = lane & 15, lk = lane >> 4;
  int swz = (lr >> 1) & 3;              // row-swizzle term (row mod 8 == lr mod 8)
  int fragcol = (lk ^ swz) * 8;         // swizzled ds_read column (shorts)
  f32x4 acc[4][4] = {};

  for (int kt = 0; kt < K; kt += BK) {
    __syncthreads();
#pragma unroll
    for (int j = 0; j < 2; ++j) {
      int chunk = j * 256 + t;
      int r = chunk >> 2;
      int kc = (chunk & 3) ^ ((chunk >> 3) & 3);   // pre-swizzled source segment
      int wavebase = (j * 256 + w * 64) * 8;       // linear LDS dest (shorts)
      int gra = row0 + r; gra = gra < M ? gra : M - 1;
      gload_lds16(A + (size_t)gra * K + kt + kc * 8, &lA[wavebase]);
      gload_lds16(BT + (size_t)(col0 + r) * K + kt + kc * 8, &lB[wavebase]);
    }
    __syncthreads();
    bf16x8 af[4], bfr[4];
#pragma unroll
    for (int mi = 0; mi < 4; ++mi)
      af[mi] = *(const bf16x8*)&lA[(wr + mi * 16 + lr) * BK + fragcol];
#pragma unroll
    for (int ni = 0; ni < 4; ++ni)
      bfr[ni] = *(const bf16x8*)&lB[(wc + ni * 16 + lr) * BK + fragcol];
#pragma unroll
    for (int mi = 0; mi < 4; ++mi)
#pragma unroll
      for (int ni = 0; ni < 4; ++ni)
        acc[mi][ni] = __builtin_amdgcn_mfma_f32_16x16x32_bf16(af[mi], bfr[ni], acc[mi][ni], 0, 0, 0);
  }

#pragma unroll
  for (int mi = 0; mi < 4; ++mi) {
#pragma unroll
    for (int r = 0; r < 4; ++r) {
      int row = row0 + wr + mi * 16 + lk * 4 + r;
      if (row >= M) continue;
      size_t orow = (size_t)(perm ? perm[row] : row);
#pragma unroll
      for (int ni = 0; ni < 4; ++ni) {
        int col = col0 + wc + ni * 16 + lr;
        float v = acc[mi][ni][r];
        if constexpr (MODE == M_QKVS) {
          v += bias[col];
          if (col < 1152)
            ((__hip_bfloat16*)out0)[orow * 1152 + col] = __float2bfloat16(v);
          else
            ((float*)out1)[orow * DD + (col - 1152)] = v;
        } else if constexpr (MODE == M_BF16) {
          ((__hip_bfloat16*)out0)[orow * Nn + col] = __float2bfloat16(v);
        } else if constexpr (MODE == M_GELU) {
          v += bias[col];
          v = 0.5f * v * (1.f + erff(v * 0.70710678118f));
          ((__hip_bfloat16*)out0)[orow * Nn + col] = __float2bfloat16(v);
        } else {  // M_RES
          v += bias[col];
          ((float*)out0)[orow * Nn + col] = v + res[orow * Nn + col];
        }
      }
    }
  }
}

// ---------------- host ----------------
extern "C" void kernel_launch(void* const* d_in, const int* in_sizes, int n_in,
                              void* d_out, int out_size, void* d_ws, size_t ws_size,
                              hipStream_t stream) {
  const float* x   = (const float*)d_in[0];
  const int*   ei  = (const int*)d_in[1];
  const float* ea  = (const float*)d_in[2];
  const float* g1  = (const float*)d_in[3];
  const float* b1  = (const float*)d_in[4];
  const float* Wq  = (const float*)d_in[5];
  const float* bq  = (const float*)d_in[6];
  const float* Wk  = (const float*)d_in[7];
  const float* bk  = (const float*)d_in[8];
  const float* Wv  = (const float*)d_in[9];
  const float* bv  = (const float*)d_in[10];
  const float* We  = (const float*)d_in[11];
  const float* Wsk = (const float*)d_in[12];
  const float* bsk = (const float*)d_in[13];
  const float* g2  = (const float*)d_in[14];
  const float* b2  = (const float*)d_in[15];
  const float* W1  = (const float*)d_in[16];
  const float* bm1 = (const float*)d_in[17];
  const float* W2  = (const float*)d_in[18];
  const float* bm2 = (const float*)d_in[19];

  int N = in_sizes[0] / DD;
  int E = in_sizes[1] / 2;

  char* ws = (char*)d_ws;
  size_t off = 0;
  auto alloc = [&](size_t bytes) -> char* {
    char* p = ws + off;
    off = (off + bytes + 255) & ~(size_t)255;
    return p;
  };

  float* bnsum = (float*)alloc(4 * DD * sizeof(float));  // sums1, sq1, sums2, sq2
  float* a1 = (float*)alloc(DD * 4);
  float* c1 = (float*)alloc(DD * 4);
  float* a2 = (float*)alloc(DD * 4);
  float* c2 = (float*)alloc(DD * 4);
  float* bqkvs = (float*)alloc(1536 * 4);
  float* bm1p = (float*)alloc(DHID * 4);
  __hip_bfloat16* WqkvsT = (__hip_bfloat16*)alloc((size_t)1536 * DD * 2);
  __hip_bfloat16* WeT = (__hip_bfloat16*)alloc((size_t)DD * DD * 2);
  __hip_bfloat16* W1T = (__hip_bfloat16*)alloc((size_t)DHID * DD * 2);
  __hip_bfloat16* W2T = (__hip_bfloat16*)alloc((size_t)DD * DHID * 2);
  __hip_bfloat16* xb = (__hip_bfloat16*)alloc((size_t)N * DD * 2);     // bf16(x)
  __hip_bfloat16* xb1 = (__hip_bfloat16*)alloc((size_t)N * DD * 2);    // bf16(x1)
  __hip_bfloat16* qkv = (__hip_bfloat16*)alloc((size_t)N * 1152 * 2);
  float* skip = (float*)alloc((size_t)N * DD * 4);
  __hip_bfloat16* eabf = (__hip_bfloat16*)alloc((size_t)E * DD * 2);
  __hip_bfloat16* ebuf = (__hip_bfloat16*)alloc((size_t)E * DD * 2);
  float* agg = (float*)alloc((size_t)N * DD * 4);
  float* x1 = (float*)alloc((size_t)N * DD * 4);
  __hip_bfloat16* hid = (__hip_bfloat16*)alloc((size_t)N * DHID * 2);
  int* deg = (int*)alloc((size_t)N * 4);
  int* cursor = (int*)alloc((size_t)N * 4);
  int* row_start = (int*)alloc((size_t)(N + 1) * 4);
  int* csr_src = (int*)alloc((size_t)E * 4);
  int* pos_of_eid = (int*)alloc((size_t)E * 4);
  (void)ws_size; (void)n_in; (void)out_size;

  hipMemsetAsync(bnsum, 0, 4 * DD * sizeof(float), stream);
  hipMemsetAsync(deg, 0, (size_t)N * 4, stream);

  // CSR build (must precede edge GEMM: it consumes pos_of_eid)
  hist_k<<<(E + 255) / 256, 256, 0, stream>>>(ei, deg, E);
  scan_k<<<1, 1024, 0, stream>>>(deg, row_start, cursor, N);
  scatter_k<<<(E + 255) / 256, 256, 0, stream>>>(ei, cursor, csr_src, pos_of_eid, E);

  // edge_attr -> bf16 (streaming)
  int e4 = E * DD / 4;
  f32_to_bf16_k<<<(e4 + 255) / 256, 256, 0, stream>>>(ea, eabf, e4);

  // BN1 stats (+x->bf16 cast) -> fold into weights
  int rpb = 128, sgrid = (N + rpb - 1) / rpb;
  bn_stats_k<<<sgrid, DD, 0, stream>>>(x, bnsum, bnsum + DD, xb, N, rpb);
  bn_finalize_k<<<2, 256, 0, stream>>>(bnsum, bnsum + DD, g1, b1, a1, c1, N);

  int wgrid = (DD * DD + 255) / 256;
  transpose_scale_k<<<wgrid, 256, 0, stream>>>(Wq, a1, WqkvsT, DD, DD);
  transpose_scale_k<<<wgrid, 256, 0, stream>>>(Wk, a1, WqkvsT + (size_t)DD * DD, DD, DD);
  transpose_scale_k<<<wgrid, 256, 0, stream>>>(Wv, a1, WqkvsT + (size_t)2 * DD * DD, DD, DD);
  transpose_scale_k<<<wgrid, 256, 0, stream>>>(Wsk, a1, WqkvsT + (size_t)3 * DD * DD, DD, DD);
  transpose_scale_k<<<wgrid, 256, 0, stream>>>(We, nullptr, WeT, DD, DD);
  transpose_scale_k<<<(DHID * DD + 255) / 256, 256, 0, stream>>>(W2, nullptr, W2T, DHID, DD);
  bias_cw_k<<<2, 256, 0, stream>>>(bq, c1, Wq, bqkvs, DD, DD);
  bias_cw_k<<<2, 256, 0, stream>>>(bk, c1, Wk, bqkvs + DD, DD, DD);
  bias_cw_k<<<2, 256, 0, stream>>>(bv, c1, Wv, bqkvs + 2 * DD, DD, DD);
  bias_cw_k<<<2, 256, 0, stream>>>(bsk, c1, Wsk, bqkvs + 3 * DD, DD, DD);

  // qkv + skip (A = bf16(x), BN folded into weights)
  dim3 gqkvs((N + BM - 1) / BM * (1536 / BN));
  gemm_k<M_QKVS><<<gqkvs, 256, 0, stream>>>(xb, WqkvsT, bqkvs, nullptr, nullptr, qkv, skip, N, DD, 1536, 1536 / BN);

  // edge features, written directly in CSR order (perm = pos_of_eid)
  dim3 ge((E + BM - 1) / BM * (DD / BN));
  gemm_k<M_BF16><<<ge, 256, 0, stream>>>(eabf, WeT, nullptr, nullptr, pos_of_eid, ebuf, nullptr, E, DD, DD, DD / BN);

  attn_k<<<(N * 64 + 255) / 256, 256, 0, stream>>>(qkv, ebuf, row_start, csr_src, agg, N);

  // residual + BN2 stats + x1->bf16 fused
  add3_bn_k<<<sgrid, DD, 0, stream>>>(x, agg, skip, x1, xb1, bnsum + 2 * DD, bnsum + 3 * DD, N, rpb);
  bn_finalize_k<<<2, 256, 0, stream>>>(bnsum + 2 * DD, bnsum + 3 * DD, g2, b2, a2, c2, N);

  transpose_scale_k<<<(DD * DHID + 255) / 256, 256, 0, stream>>>(W1, a2, W1T, DD, DHID);
  bias_cw_k<<<3, 256, 0, stream>>>(bm1, c2, W1, bm1p, DD, DHID);

  // MLP
  dim3 gm1((N + BM - 1) / BM * (DHID / BN));
  gemm_k<M_GELU><<<gm1, 256, 0, stream>>>(xb1, W1T, bm1p, nullptr, nullptr, hid, nullptr, N, DD, DHID, DHID / BN);

  dim3 gm2((N + BM - 1) / BM * (DD / BN));
  gemm_k<M_RES><<<gm2, 256, 0, stream>>>(hid, W2T, bm2, x1, nullptr, (float*)d_out, nullptr, N, DHID, DD, DD / BN);
}

// Round 4
// 1110.732 us; speedup vs baseline: 1.0158x; 1.0158x over previous
//
#include <hip/hip_runtime.h>
#include <hip/hip_bf16.h>

#define DD 384
#define NH 6
#define DHID 768

typedef __attribute__((ext_vector_type(8))) short bf16x8;
typedef __attribute__((ext_vector_type(4))) float f32x4;

__device__ __forceinline__ void gload_lds16(const void* gsrc, void* ldst) {
  __builtin_amdgcn_global_load_lds((const __attribute__((address_space(1))) void*)gsrc,
                                   (__attribute__((address_space(3))) void*)ldst,
                                   16, 0, 0);
}

union BPack { ushort4 u; __hip_bfloat16 b[4]; };

// ---------------- BatchNorm stats (+ fused bf16 cast of raw x) ----------------
__global__ __launch_bounds__(384) void bn_stats_k(const float* __restrict__ x, float* __restrict__ sums,
                                                  float* __restrict__ sq, __hip_bfloat16* __restrict__ xb,
                                                  int N, int rpb) {
  int d = threadIdx.x;
  int r0 = blockIdx.x * rpb;
  int r1 = min(r0 + rpb, N);
  float s = 0.f, ss = 0.f;
  for (int r = r0; r < r1; ++r) {
    size_t i = (size_t)r * DD + d;
    float v = x[i];
    s += v; ss += v * v;
    xb[i] = __float2bfloat16(v);
  }
  atomicAdd(&sums[d], s);
  atomicAdd(&sq[d], ss);
}

__global__ void bn_finalize_k(const float* sums, const float* sq, const float* g, const float* b,
                              float* a, float* c, int N) {
  int d = blockIdx.x * blockDim.x + threadIdx.x;
  if (d >= DD) return;
  float inv = 1.f / (float)N;
  float mu = sums[d] * inv;
  float var = sq[d] * inv - mu * mu;
  float rs = rsqrtf(var + 1e-5f);
  a[d] = rs * g[d];
  c[d] = b[d] - mu * rs * g[d];
}

// W' = bf16(diag(a) @ W), transposed to [Nout, K]; a == nullptr -> plain transpose
__global__ void transpose_scale_k(const float* __restrict__ in, const float* __restrict__ a,
                                  __hip_bfloat16* __restrict__ out, int K, int Nout) {
  int i = blockIdx.x * blockDim.x + threadIdx.x;
  if (i >= K * Nout) return;
  int k = i / Nout, n = i % Nout;
  float v = in[i];
  if (a) v *= a[k];
  out[(size_t)n * K + k] = __float2bfloat16(v);
}

// out[n] = bias[n] + sum_k c[k] * W[k][n]   (exact f32)
__global__ void bias_cw_k(const float* __restrict__ bias, const float* __restrict__ c,
                          const float* __restrict__ W, float* __restrict__ out, int K, int Nn) {
  int n = blockIdx.x * blockDim.x + threadIdx.x;
  if (n >= Nn) return;
  float s = bias ? bias[n] : 0.f;
  for (int k = 0; k < K; ++k) s += c[k] * W[(size_t)k * Nn + n];
  out[n] = s;
}

__global__ void f32_to_bf16_k(const float* __restrict__ in, __hip_bfloat16* __restrict__ out, int total4) {
  int i = blockIdx.x * blockDim.x + threadIdx.x;
  if (i >= total4) return;
  float4 v = ((const float4*)in)[i];
  BPack p;
  p.b[0] = __float2bfloat16(v.x);
  p.b[1] = __float2bfloat16(v.y);
  p.b[2] = __float2bfloat16(v.z);
  p.b[3] = __float2bfloat16(v.w);
  ((ushort4*)out)[i] = p.u;
}

// x1 = x + agg + skip, fused BN2 stats + fused bf16 cast of x1
__global__ __launch_bounds__(384) void add3_bn_k(const float* __restrict__ x, const float* __restrict__ agg,
                                                 const float* __restrict__ skip, float* __restrict__ x1,
                                                 __hip_bfloat16* __restrict__ xb1,
                                                 float* __restrict__ sums, float* __restrict__ sq,
                                                 int N, int rpb) {
  int d = threadIdx.x;
  int r0 = blockIdx.x * rpb;
  int r1 = min(r0 + rpb, N);
  float s = 0.f, ss = 0.f;
  for (int r = r0; r < r1; ++r) {
    size_t i = (size_t)r * DD + d;
    float v = x[i] + agg[i] + skip[i];
    x1[i] = v;
    xb1[i] = __float2bfloat16(v);
    s += v; ss += v * v;
  }
  atomicAdd(&sums[d], s);
  atomicAdd(&sq[d], ss);
}

// ---------------- CSR build ----------------
__global__ void hist_k(const int* __restrict__ ei, int* __restrict__ deg, int E) {
  int i = blockIdx.x * blockDim.x + threadIdx.x;
  if (i < E) atomicAdd(&deg[ei[E + i]], 1);
}

__global__ __launch_bounds__(1024) void scan_k(const int* __restrict__ deg, int* __restrict__ row_start,
                                               int* __restrict__ cursor, int N) {
  __shared__ int part[1024];
  int t = threadIdx.x;
  int ch = (N + 1023) / 1024;
  int c0 = t * ch, c1 = min(c0 + ch, N);
  int s = 0;
  for (int i = c0; i < c1; ++i) s += deg[i];
  part[t] = s;
  __syncthreads();
  for (int off = 1; off < 1024; off <<= 1) {
    int v = (t >= off) ? part[t - off] : 0;
    __syncthreads();
    part[t] += v;
    __syncthreads();
  }
  int run = part[t] - s;
  for (int i = c0; i < c1; ++i) {
    row_start[i] = run; cursor[i] = run; run += deg[i];
  }
  if (t == 1023) row_start[N] = part[1023];
}

__global__ void scatter_k(const int* __restrict__ ei, int* __restrict__ cursor,
                          int* __restrict__ csr_src, int* __restrict__ csr_eid, int E) {
  int i = blockIdx.x * blockDim.x + threadIdx.x;
  if (i >= E) return;
  int s = ei[i], d = ei[E + i];
  int pos = atomicAdd(&cursor[d], 1);
  csr_src[pos] = s;
  csr_eid[pos] = i;
}

// ---------------- attention (one wave per node) ----------------
__global__ __launch_bounds__(256) void attn_k(const __hip_bfloat16* __restrict__ qkv,
                                              const __hip_bfloat16* __restrict__ ebuf,
                                              const int* __restrict__ row_start,
                                              const int* __restrict__ csr_src,
                                              const int* __restrict__ csr_eid,
                                              float* __restrict__ agg, int N) {
  int wid = (blockIdx.x * blockDim.x + threadIdx.x) >> 6;
  int lane = threadIdx.x & 63;
  if (wid >= N) return;
  float q[NH], acc[NH], psum[NH];
#pragma unroll
  for (int h = 0; h < NH; ++h) {
    q[h] = __bfloat162float(qkv[(size_t)wid * 1152 + h * 64 + lane]);
    acc[h] = 0.f; psum[h] = 0.f;
  }
  int i0 = row_start[wid], i1 = row_start[wid + 1];
  for (int i = i0; i < i1; ++i) {
    int s = csr_src[i];
    size_t eb = (size_t)csr_eid[i] * DD;
    size_t sb = (size_t)s * 1152;
    float ev[NH], p[NH];
#pragma unroll
    for (int h = 0; h < NH; ++h)
      ev[h] = __bfloat162float(ebuf[eb + h * 64 + lane]);
#pragma unroll
    for (int h = 0; h < NH; ++h) {
      float kk = __bfloat162float(qkv[sb + 384 + h * 64 + lane]);
      float t = q[h] * (kk + ev[h]);
#pragma unroll
      for (int off = 32; off > 0; off >>= 1) t += __shfl_xor(t, off);
      p[h] = expf(t * 0.125f);
    }
#pragma unroll
    for (int h = 0; h < NH; ++h) {
      float vv = __bfloat162float(qkv[sb + 768 + h * 64 + lane]) + ev[h];
      acc[h] += p[h] * vv;
      psum[h] += p[h];
    }
  }
#pragma unroll
  for (int h = 0; h < NH; ++h)
    agg[(size_t)wid * DD + h * 64 + lane] = psum[h] > 0.f ? acc[h] / psum[h] : 0.f;
}

// ---------------- GEMM (round-1 structure: 2D grid, linear LDS, global_load_lds) ----------------
#define BM 128
#define BN 128
#define BK 32

enum { M_QKVS = 0, M_BF16 = 1, M_GELU = 2, M_RES = 3 };

template <int MODE>
__device__ __forceinline__ void gemm_body(const __hip_bfloat16* __restrict__ A,
                                          const __hip_bfloat16* __restrict__ BT,
                                          const float* __restrict__ bias,
                                          const float* __restrict__ res,
                                          void* __restrict__ out0, void* __restrict__ out1,
                                          int M, int K, int Nn) {
  __shared__ short lA[BM * BK];
  __shared__ short lB[BN * BK];
  int t = threadIdx.x;
  int lane = t & 63, w = t >> 6;
  int wr = (w >> 1) * 64, wc = (w & 1) * 64;
  int row0 = blockIdx.x * BM, col0 = blockIdx.y * BN;
  int lr = lane & 15, lk = lane >> 4;
  f32x4 acc[4][4] = {};

  for (int kt = 0; kt < K; kt += BK) {
    __syncthreads();
#pragma unroll
    for (int j = 0; j < 2; ++j) {
      int chunk = j * 256 + t;
      int r = chunk >> 2, kc = chunk & 3;
      int wavebase = (j * 256 + w * 64) * 8;  // linear LDS dest (shorts)
      int gra = row0 + r; gra = gra < M ? gra : M - 1;
      gload_lds16(A + (size_t)gra * K + kt + kc * 8, &lA[wavebase]);
      gload_lds16(BT + (size_t)(col0 + r) * K + kt + kc * 8, &lB[wavebase]);
    }
    __syncthreads();
    bf16x8 af[4], bfr[4];
#pragma unroll
    for (int mi = 0; mi < 4; ++mi)
      af[mi] = *(const bf16x8*)&lA[(wr + mi * 16 + lr) * BK + lk * 8];
#pragma unroll
    for (int ni = 0; ni < 4; ++ni)
      bfr[ni] = *(const bf16x8*)&lB[(wc + ni * 16 + lr) * BK + lk * 8];
#pragma unroll
    for (int mi = 0; mi < 4; ++mi)
#pragma unroll
      for (int ni = 0; ni < 4; ++ni)
        acc[mi][ni] = __builtin_amdgcn_mfma_f32_16x16x32_bf16(af[mi], bfr[ni], acc[mi][ni], 0, 0, 0);
  }

#pragma unroll
  for (int mi = 0; mi < 4; ++mi) {
#pragma unroll
    for (int r = 0; r < 4; ++r) {
      int row = row0 + wr + mi * 16 + lk * 4 + r;
      if (row >= M) continue;
#pragma unroll
      for (int ni = 0; ni < 4; ++ni) {
        int col = col0 + wc + ni * 16 + lr;
        float v = acc[mi][ni][r];
        if constexpr (MODE == M_QKVS) {
          v += bias[col];
          if (col < 1152)
            ((__hip_bfloat16*)out0)[(size_t)row * 1152 + col] = __float2bfloat16(v);
          else
            ((float*)out1)[(size_t)row * DD + (col - 1152)] = v;
        } else if constexpr (MODE == M_BF16) {
          ((__hip_bfloat16*)out0)[(size_t)row * Nn + col] = __float2bfloat16(v);
        } else if constexpr (MODE == M_GELU) {
          v += bias[col];
          v = 0.5f * v * (1.f + erff(v * 0.70710678118f));
          ((__hip_bfloat16*)out0)[(size_t)row * Nn + col] = __float2bfloat16(v);
        } else {  // M_RES
          v += bias[col];
          ((float*)out0)[(size_t)row * Nn + col] = v + res[(size_t)row * Nn + col];
        }
      }
    }
  }
}

__global__ __launch_bounds__(256) void gemm_qkvs(const __hip_bfloat16* A, const __hip_bfloat16* BT,
                                                 const float* bias, void* out0, void* out1, int M) {
  gemm_body<M_QKVS>(A, BT, bias, nullptr, out0, out1, M, DD, 1536);
}
__global__ __launch_bounds__(256) void gemm_edge(const __hip_bfloat16* A, const __hip_bfloat16* BT,
                                                 void* out0, int M) {
  gemm_body<M_BF16>(A, BT, nullptr, nullptr, out0, nullptr, M, DD, DD);
}
__global__ __launch_bounds__(256) void gemm_mlp1(const __hip_bfloat16* A, const __hip_bfloat16* BT,
                                                 const float* bias, void* out0, int M) {
  gemm_body<M_GELU>(A, BT, bias, nullptr, out0, nullptr, M, DD, DHID);
}
__global__ __launch_bounds__(256) void gemm_mlp2(const __hip_bfloat16* A, const __hip_bfloat16* BT,
                                                 const float* bias, const float* res, void* out0, int M) {
  gemm_body<M_RES>(A, BT, bias, res, out0, nullptr, M, DHID, DD);
}

// ---------------- host ----------------
extern "C" void kernel_launch(void* const* d_in, const int* in_sizes, int n_in,
                              void* d_out, int out_size, void* d_ws, size_t ws_size,
                              hipStream_t stream) {
  const float* x   = (const float*)d_in[0];
  const int*   ei  = (const int*)d_in[1];
  const float* ea  = (const float*)d_in[2];
  const float* g1  = (const float*)d_in[3];
  const float* b1  = (const float*)d_in[4];
  const float* Wq  = (const float*)d_in[5];
  const float* bq  = (const float*)d_in[6];
  const float* Wk  = (const float*)d_in[7];
  const float* bk  = (const float*)d_in[8];
  const float* Wv  = (const float*)d_in[9];
  const float* bv  = (const float*)d_in[10];
  const float* We  = (const float*)d_in[11];
  const float* Wsk = (const float*)d_in[12];
  const float* bsk = (const float*)d_in[13];
  const float* g2  = (const float*)d_in[14];
  const float* b2  = (const float*)d_in[15];
  const float* W1  = (const float*)d_in[16];
  const float* bm1 = (const float*)d_in[17];
  const float* W2  = (const float*)d_in[18];
  const float* bm2 = (const float*)d_in[19];

  int N = in_sizes[0] / DD;
  int E = in_sizes[1] / 2;

  char* ws = (char*)d_ws;
  size_t off = 0;
  auto alloc = [&](size_t bytes) -> char* {
    char* p = ws + off;
    off = (off + bytes + 255) & ~(size_t)255;
    return p;
  };

  float* bnsum = (float*)alloc(4 * DD * sizeof(float));  // sums1, sq1, sums2, sq2
  float* a1 = (float*)alloc(DD * 4);
  float* c1 = (float*)alloc(DD * 4);
  float* a2 = (float*)alloc(DD * 4);
  float* c2 = (float*)alloc(DD * 4);
  float* bqkvs = (float*)alloc(1536 * 4);
  float* bm1p = (float*)alloc(DHID * 4);
  __hip_bfloat16* WqkvsT = (__hip_bfloat16*)alloc((size_t)1536 * DD * 2);
  __hip_bfloat16* WeT = (__hip_bfloat16*)alloc((size_t)DD * DD * 2);
  __hip_bfloat16* W1T = (__hip_bfloat16*)alloc((size_t)DHID * DD * 2);
  __hip_bfloat16* W2T = (__hip_bfloat16*)alloc((size_t)DD * DHID * 2);
  __hip_bfloat16* xb = (__hip_bfloat16*)alloc((size_t)N * DD * 2);     // bf16(x)
  __hip_bfloat16* xb1 = (__hip_bfloat16*)alloc((size_t)N * DD * 2);    // bf16(x1)
  __hip_bfloat16* qkv = (__hip_bfloat16*)alloc((size_t)N * 1152 * 2);
  float* skip = (float*)alloc((size_t)N * DD * 4);
  __hip_bfloat16* eabf = (__hip_bfloat16*)alloc((size_t)E * DD * 2);
  __hip_bfloat16* ebuf = (__hip_bfloat16*)alloc((size_t)E * DD * 2);
  float* agg = (float*)alloc((size_t)N * DD * 4);
  float* x1 = (float*)alloc((size_t)N * DD * 4);
  __hip_bfloat16* hid = (__hip_bfloat16*)alloc((size_t)N * DHID * 2);
  int* deg = (int*)alloc((size_t)N * 4);
  int* cursor = (int*)alloc((size_t)N * 4);
  int* row_start = (int*)alloc((size_t)(N + 1) * 4);
  int* csr_src = (int*)alloc((size_t)E * 4);
  int* csr_eid = (int*)alloc((size_t)E * 4);
  (void)ws_size; (void)n_in; (void)out_size;

  hipMemsetAsync(bnsum, 0, 4 * DD * sizeof(float), stream);
  hipMemsetAsync(deg, 0, (size_t)N * 4, stream);

  // CSR build
  hist_k<<<(E + 255) / 256, 256, 0, stream>>>(ei, deg, E);
  scan_k<<<1, 1024, 0, stream>>>(deg, row_start, cursor, N);
  scatter_k<<<(E + 255) / 256, 256, 0, stream>>>(ei, cursor, csr_src, csr_eid, E);

  // edge_attr -> bf16 (streaming)
  int e4 = E * DD / 4;
  f32_to_bf16_k<<<(e4 + 255) / 256, 256, 0, stream>>>(ea, eabf, e4);

  // BN1 stats (+x->bf16 cast) -> fold into weights
  int rpb = 128, sgrid = (N + rpb - 1) / rpb;
  bn_stats_k<<<sgrid, DD, 0, stream>>>(x, bnsum, bnsum + DD, xb, N, rpb);
  bn_finalize_k<<<2, 256, 0, stream>>>(bnsum, bnsum + DD, g1, b1, a1, c1, N);

  int wgrid = (DD * DD + 255) / 256;
  transpose_scale_k<<<wgrid, 256, 0, stream>>>(Wq, a1, WqkvsT, DD, DD);
  transpose_scale_k<<<wgrid, 256, 0, stream>>>(Wk, a1, WqkvsT + (size_t)DD * DD, DD, DD);
  transpose_scale_k<<<wgrid, 256, 0, stream>>>(Wv, a1, WqkvsT + (size_t)2 * DD * DD, DD, DD);
  transpose_scale_k<<<wgrid, 256, 0, stream>>>(Wsk, a1, WqkvsT + (size_t)3 * DD * DD, DD, DD);
  transpose_scale_k<<<wgrid, 256, 0, stream>>>(We, nullptr, WeT, DD, DD);
  transpose_scale_k<<<(DHID * DD + 255) / 256, 256, 0, stream>>>(W2, nullptr, W2T, DHID, DD);
  bias_cw_k<<<2, 256, 0, stream>>>(bq, c1, Wq, bqkvs, DD, DD);
  bias_cw_k<<<2, 256, 0, stream>>>(bk, c1, Wk, bqkvs + DD, DD, DD);
  bias_cw_k<<<2, 256, 0, stream>>>(bv, c1, Wv, bqkvs + 2 * DD, DD, DD);
  bias_cw_k<<<2, 256, 0, stream>>>(bsk, c1, Wsk, bqkvs + 3 * DD, DD, DD);

  // qkv + skip (A = bf16(x), BN folded into weights)
  dim3 gqkvs((N + BM - 1) / BM, 1536 / BN);
  gemm_qkvs<<<gqkvs, 256, 0, stream>>>(xb, WqkvsT, bqkvs, qkv, skip, N);

  // edge features
  dim3 ge((E + BM - 1) / BM, DD / BN);
  gemm_edge<<<ge, 256, 0, stream>>>(eabf, WeT, ebuf, E);

  attn_k<<<(N * 64 + 255) / 256, 256, 0, stream>>>(qkv, ebuf, row_start, csr_src, csr_eid, agg, N);

  // residual + BN2 stats + x1->bf16 fused
  add3_bn_k<<<sgrid, DD, 0, stream>>>(x, agg, skip, x1, xb1, bnsum + 2 * DD, bnsum + 3 * DD, N, rpb);
  bn_finalize_k<<<2, 256, 0, stream>>>(bnsum + 2 * DD, bnsum + 3 * DD, g2, b2, a2, c2, N);

  transpose_scale_k<<<(DD * DHID + 255) / 256, 256, 0, stream>>>(W1, a2, W1T, DD, DHID);
  bias_cw_k<<<3, 256, 0, stream>>>(bm1, c2, W1, bm1p, DD, DHID);

  // MLP
  dim3 gm1((N + BM - 1) / BM, DHID / BN);
  gemm_mlp1<<<gm1, 256, 0, stream>>>(xb1, W1T, bm1p, hid, N);

  dim3 gm2((N + BM - 1) / BM, DD / BN);
  gemm_mlp2<<<gm2, 256, 0, stream>>>(hid, W2T, bm2, x1, (float*)d_out, N);
}

// Round 5
// 683.847 us; speedup vs baseline: 1.6499x; 1.6242x over previous
//

#include <hip/hip_runtime.h>
#include <hip/hip_bf16.h>

#define DD 384
#define NH 6
#define DHID 768

typedef __attribute__((ext_vector_type(8))) short bf16x8;
typedef __attribute__((ext_vector_type(4))) float f32x4;

__device__ __forceinline__ void gload_lds16(const void* gsrc, void* ldst) {
  __builtin_amdgcn_global_load_lds((const __attribute__((address_space(1))) void*)gsrc,
                                   (__attribute__((address_space(3))) void*)ldst,
                                   16, 0, 0);
}

// ---------------- BatchNorm ----------------
__global__ __launch_bounds__(384) void bn_stats_k(const float* __restrict__ x, float* __restrict__ sums,
                                                  float* __restrict__ sq, int N, int rpb) {
  int d = threadIdx.x;
  int r0 = blockIdx.x * rpb;
  int r1 = min(r0 + rpb, N);
  float s = 0.f, ss = 0.f;
  for (int r = r0; r < r1; ++r) {
    float v = x[(size_t)r * DD + d];
    s += v; ss += v * v;
  }
  atomicAdd(&sums[d], s);
  atomicAdd(&sq[d], ss);
}

__global__ void bn_finalize_k(const float* sums, const float* sq, const float* g, const float* b,
                              float* a, float* c, int N) {
  int d = blockIdx.x * blockDim.x + threadIdx.x;
  if (d >= DD) return;
  float inv = 1.f / (float)N;
  float mu = sums[d] * inv;
  float var = sq[d] * inv - mu * mu;
  float rs = rsqrtf(var + 1e-5f);
  a[d] = rs * g[d];
  c[d] = b[d] - mu * rs * g[d];
}

union BPack { ushort4 u; __hip_bfloat16 b[4]; };

__global__ void norm_to_bf16_k(const float* __restrict__ x, const float* __restrict__ a,
                               const float* __restrict__ c, __hip_bfloat16* __restrict__ h, int total4) {
  int i = blockIdx.x * blockDim.x + threadIdx.x;
  if (i >= total4) return;
  float4 v = ((const float4*)x)[i];
  int d0 = (i * 4) % DD;
  float4 av = *(const float4*)(a + d0);
  float4 cv = *(const float4*)(c + d0);
  BPack p;
  p.b[0] = __float2bfloat16(v.x * av.x + cv.x);
  p.b[1] = __float2bfloat16(v.y * av.y + cv.y);
  p.b[2] = __float2bfloat16(v.z * av.z + cv.z);
  p.b[3] = __float2bfloat16(v.w * av.w + cv.w);
  ((ushort4*)h)[i] = p.u;
}

__global__ void f32_to_bf16_k(const float* __restrict__ in, __hip_bfloat16* __restrict__ out, int total4) {
  int i = blockIdx.x * blockDim.x + threadIdx.x;
  if (i >= total4) return;
  float4 v = ((const float4*)in)[i];
  BPack p;
  p.b[0] = __float2bfloat16(v.x);
  p.b[1] = __float2bfloat16(v.y);
  p.b[2] = __float2bfloat16(v.z);
  p.b[3] = __float2bfloat16(v.w);
  ((ushort4*)out)[i] = p.u;
}

__global__ void transpose_bf16_k(const float* __restrict__ in, __hip_bfloat16* __restrict__ out,
                                 int K, int Nout) {
  int i = blockIdx.x * blockDim.x + threadIdx.x;
  if (i >= K * Nout) return;
  int k = i / Nout, n = i % Nout;
  out[(size_t)n * K + k] = __float2bfloat16(in[i]);
}

__global__ void concat_bias_k(const float* bq, const float* bk, const float* bv, const float* bs,
                              float* out) {
  int i = blockIdx.x * blockDim.x + threadIdx.x;
  if (i >= 1536) return;
  float v = (i < 384) ? bq[i] : (i < 768) ? bk[i - 384] : (i < 1152) ? bv[i - 768] : bs[i - 1152];
  out[i] = v;
}

__global__ void add3_k(const float* __restrict__ x, const float* __restrict__ agg,
                       const float* __restrict__ skip, float* __restrict__ x1, int total4) {
  int i = blockIdx.x * blockDim.x + threadIdx.x;
  if (i >= total4) return;
  float4 a = ((const float4*)x)[i];
  float4 b = ((const float4*)agg)[i];
  float4 c = ((const float4*)skip)[i];
  float4 o;
  o.x = a.x + b.x + c.x; o.y = a.y + b.y + c.y;
  o.z = a.z + b.z + c.z; o.w = a.w + b.w + c.w;
  ((float4*)x1)[i] = o;
}

// ---------------- CSR build ----------------
__global__ void hist_k(const int* __restrict__ ei, int* __restrict__ deg, int E) {
  int i = blockIdx.x * blockDim.x + threadIdx.x;
  if (i < E) atomicAdd(&deg[ei[E + i]], 1);
}

__global__ __launch_bounds__(1024) void scan_k(const int* __restrict__ deg, int* __restrict__ row_start,
                                               int* __restrict__ cursor, int N) {
  __shared__ int part[1024];
  int t = threadIdx.x;
  int ch = (N + 1023) / 1024;
  int c0 = t * ch, c1 = min(c0 + ch, N);
  int s = 0;
  for (int i = c0; i < c1; ++i) s += deg[i];
  part[t] = s;
  __syncthreads();
  for (int off = 1; off < 1024; off <<= 1) {
    int v = (t >= off) ? part[t - off] : 0;
    __syncthreads();
    part[t] += v;
    __syncthreads();
  }
  int run = part[t] - s;
  for (int i = c0; i < c1; ++i) {
    row_start[i] = run; cursor[i] = run; run += deg[i];
  }
  if (t == 1023) row_start[N] = part[1023];
}

__global__ void scatter_k(const int* __restrict__ ei, int* __restrict__ cursor,
                          int* __restrict__ csr_src, int* __restrict__ csr_eid, int E) {
  int i = blockIdx.x * blockDim.x + threadIdx.x;
  if (i >= E) return;
  int s = ei[i], d = ei[E + i];
  int pos = atomicAdd(&cursor[d], 1);
  csr_src[pos] = s;
  csr_eid[pos] = i;
}

// ---------------- attention (one wave per node) ----------------
__global__ __launch_bounds__(256) void attn_k(const __hip_bfloat16* __restrict__ qkv,
                                              const __hip_bfloat16* __restrict__ ebuf,
                                              const int* __restrict__ row_start,
                                              const int* __restrict__ csr_src,
                                              const int* __restrict__ csr_eid,
                                              float* __restrict__ agg, int N) {
  int wid = (blockIdx.x * blockDim.x + threadIdx.x) >> 6;
  int lane = threadIdx.x & 63;
  if (wid >= N) return;
  float q[NH], acc[NH], psum[NH];
#pragma unroll
  for (int h = 0; h < NH; ++h) {
    q[h] = __bfloat162float(qkv[(size_t)wid * 1152 + h * 64 + lane]);
    acc[h] = 0.f; psum[h] = 0.f;
  }
  int i0 = row_start[wid], i1 = row_start[wid + 1];
  for (int i = i0; i < i1; ++i) {
    int s = csr_src[i];
    size_t eb = (size_t)csr_eid[i] * DD;
    size_t sb = (size_t)s * 1152;
    float ev[NH], p[NH];
#pragma unroll
    for (int h = 0; h < NH; ++h)
      ev[h] = __bfloat162float(ebuf[eb + h * 64 + lane]);
#pragma unroll
    for (int h = 0; h < NH; ++h) {
      float kk = __bfloat162float(qkv[sb + 384 + h * 64 + lane]);
      float t = q[h] * (kk + ev[h]);
#pragma unroll
      for (int off = 32; off > 0; off >>= 1) t += __shfl_xor(t, off);
      p[h] = expf(t * 0.125f);
    }
#pragma unroll
    for (int h = 0; h < NH; ++h) {
      float vv = __bfloat162float(qkv[sb + 768 + h * 64 + lane]) + ev[h];
      acc[h] += p[h] * vv;
      psum[h] += p[h];
    }
  }
#pragma unroll
  for (int h = 0; h < NH; ++h)
    agg[(size_t)wid * DD + h * 64 + lane] = psum[h] > 0.f ? acc[h] / psum[h] : 0.f;
}

// ---------------- GEMM (bf16 MFMA, 128x128 tile, BK=32, B pre-transposed) ----------------
#define BM 128
#define BN 128
#define BK 32

enum { M_QKVS = 0, M_BF16 = 1, M_GELU = 2, M_RES = 3 };

template <int MODE>
__global__ __launch_bounds__(256) void gemm_k(const __hip_bfloat16* __restrict__ A,
                                              const __hip_bfloat16* __restrict__ BT,
                                              const float* __restrict__ bias,
                                              const float* __restrict__ res,
                                              void* __restrict__ out0, void* __restrict__ out1,
                                              int M, int K, int Nn) {
  __shared__ short lA[BM * BK];
  __shared__ short lB[BN * BK];
  int t = threadIdx.x;
  int lane = t & 63, w = t >> 6;
  int wr = (w >> 1) * 64, wc = (w & 1) * 64;
  int row0 = blockIdx.x * BM, col0 = blockIdx.y * BN;
  int lr = lane & 15, lk = lane >> 4;
  f32x4 acc[4][4] = {};

  for (int kt = 0; kt < K; kt += BK) {
    __syncthreads();
#pragma unroll
    for (int j = 0; j < 2; ++j) {
      int chunk = j * 256 + t;
      int r = chunk >> 2, kc = chunk & 3;
      int wavebase = (j * 256 + w * 64) * 8;  // in shorts (16B chunks per lane)
      int gra = row0 + r; gra = gra < M ? gra : M - 1;
      gload_lds16(A + (size_t)gra * K + kt + kc * 8, &lA[wavebase]);
      int grb = col0 + r;
      gload_lds16(BT + (size_t)grb * K + kt + kc * 8, &lB[wavebase]);
    }
    __syncthreads();
    bf16x8 af[4], bfr[4];
#pragma unroll
    for (int mi = 0; mi < 4; ++mi)
      af[mi] = *(const bf16x8*)&lA[(wr + mi * 16 + lr) * BK + lk * 8];
#pragma unroll
    for (int ni = 0; ni < 4; ++ni)
      bfr[ni] = *(const bf16x8*)&lB[(wc + ni * 16 + lr) * BK + lk * 8];
#pragma unroll
    for (int mi = 0; mi < 4; ++mi)
#pragma unroll
      for (int ni = 0; ni < 4; ++ni)
        acc[mi][ni] = __builtin_amdgcn_mfma_f32_16x16x32_bf16(af[mi], bfr[ni], acc[mi][ni], 0, 0, 0);
  }

#pragma unroll
  for (int mi = 0; mi < 4; ++mi) {
#pragma unroll
    for (int r = 0; r < 4; ++r) {
      int row = row0 + wr + mi * 16 + lk * 4 + r;
      if (row >= M) continue;
#pragma unroll
      for (int ni = 0; ni < 4; ++ni) {
        int col = col0 + wc + ni * 16 + lr;
        float v = acc[mi][ni][r];
        if constexpr (MODE == M_QKVS) {
          v += bias[col];
          if (col < 1152)
            ((__hip_bfloat16*)out0)[(size_t)row * 1152 + col] = __float2bfloat16(v);
          else
            ((float*)out1)[(size_t)row * DD + (col - 1152)] = v;
        } else if constexpr (MODE == M_BF16) {
          ((__hip_bfloat16*)out0)[(size_t)row * Nn + col] = __float2bfloat16(v);
        } else if constexpr (MODE == M_GELU) {
          v += bias[col];
          v = 0.5f * v * (1.f + erff(v * 0.70710678118f));
          ((__hip_bfloat16*)out0)[(size_t)row * Nn + col] = __float2bfloat16(v);
        } else {  // M_RES
          v += bias[col];
          ((float*)out0)[(size_t)row * Nn + col] = v + res[(size_t)row * Nn + col];
        }
      }
    }
  }
}

// ---------------- host ----------------
extern "C" void kernel_launch(void* const* d_in, const int* in_sizes, int n_in,
                              void* d_out, int out_size, void* d_ws, size_t ws_size,
                              hipStream_t stream) {
  const float* x   = (const float*)d_in[0];
  const int*   ei  = (const int*)d_in[1];
  const float* ea  = (const float*)d_in[2];
  const float* g1  = (const float*)d_in[3];
  const float* b1  = (const float*)d_in[4];
  const float* Wq  = (const float*)d_in[5];
  const float* bq  = (const float*)d_in[6];
  const float* Wk  = (const float*)d_in[7];
  const float* bk  = (const float*)d_in[8];
  const float* Wv  = (const float*)d_in[9];
  const float* bv  = (const float*)d_in[10];
  const float* We  = (const float*)d_in[11];
  const float* Wsk = (const float*)d_in[12];
  const float* bsk = (const float*)d_in[13];
  const float* g2  = (const float*)d_in[14];
  const float* b2  = (const float*)d_in[15];
  const float* W1  = (const float*)d_in[16];
  const float* bm1 = (const float*)d_in[17];
  const float* W2  = (const float*)d_in[18];
  const float* bm2 = (const float*)d_in[19];

  int N = in_sizes[0] / DD;
  int E = in_sizes[1] / 2;

  char* ws = (char*)d_ws;
  size_t off = 0;
  auto alloc = [&](size_t bytes) -> char* {
    char* p = ws + off;
    off = (off + bytes + 255) & ~(size_t)255;
    return p;
  };

  float* bnsum = (float*)alloc(4 * DD * sizeof(float));  // sums1, sq1, sums2, sq2
  float* a1 = (float*)alloc(DD * 4);
  float* c1 = (float*)alloc(DD * 4);
  float* a2 = (float*)alloc(DD * 4);
  float* c2 = (float*)alloc(DD * 4);
  float* bqkvs = (float*)alloc(1536 * 4);
  __hip_bfloat16* WqkvsT = (__hip_bfloat16*)alloc((size_t)1536 * DD * 2);
  __hip_bfloat16* WeT = (__hip_bfloat16*)alloc((size_t)DD * DD * 2);
  __hip_bfloat16* W1T = (__hip_bfloat16*)alloc((size_t)DHID * DD * 2);
  __hip_bfloat16* W2T = (__hip_bfloat16*)alloc((size_t)DD * DHID * 2);
  __hip_bfloat16* hbuf = (__hip_bfloat16*)alloc((size_t)N * DD * 2);   // h, later h2
  __hip_bfloat16* qkv = (__hip_bfloat16*)alloc((size_t)N * 1152 * 2);
  float* skip = (float*)alloc((size_t)N * DD * 4);
  __hip_bfloat16* eabf = (__hip_bfloat16*)alloc((size_t)E * DD * 2);   // later reused as hid
  __hip_bfloat16* ebuf = (__hip_bfloat16*)alloc((size_t)E * DD * 2);
  float* agg = (float*)alloc((size_t)N * DD * 4);
  float* x1 = (float*)alloc((size_t)N * DD * 4);
  int* deg = (int*)alloc((size_t)N * 4);
  int* cursor = (int*)alloc((size_t)N * 4);
  int* row_start = (int*)alloc((size_t)(N + 1) * 4);
  int* csr_src = (int*)alloc((size_t)E * 4);
  int* csr_eid = (int*)alloc((size_t)E * 4);
  __hip_bfloat16* hid = eabf;  // [N, 768] fits in [E, 384] region
  (void)ws_size; (void)n_in; (void)out_size;

  hipMemsetAsync(bnsum, 0, 4 * DD * sizeof(float), stream);
  hipMemsetAsync(deg, 0, (size_t)N * 4, stream);

  int rpb = 128, sgrid = (N + rpb - 1) / rpb;
  bn_stats_k<<<sgrid, DD, 0, stream>>>(x, bnsum, bnsum + DD, N, rpb);
  bn_finalize_k<<<2, 256, 0, stream>>>(bnsum, bnsum + DD, g1, b1, a1, c1, N);

  int t4 = N * DD / 4;
  norm_to_bf16_k<<<(t4 + 255) / 256, 256, 0, stream>>>(x, a1, c1, hbuf, t4);

  int wgrid = (DD * DD + 255) / 256;
  transpose_bf16_k<<<wgrid, 256, 0, stream>>>(Wq, WqkvsT, DD, DD);
  transpose_bf16_k<<<wgrid, 256, 0, stream>>>(Wk, WqkvsT + (size_t)DD * DD, DD, DD);
  transpose_bf16_k<<<wgrid, 256, 0, stream>>>(Wv, WqkvsT + (size_t)2 * DD * DD, DD, DD);
  transpose_bf16_k<<<wgrid, 256, 0, stream>>>(Wsk, WqkvsT + (size_t)3 * DD * DD, DD, DD);
  transpose_bf16_k<<<wgrid, 256, 0, stream>>>(We, WeT, DD, DD);
  transpose_bf16_k<<<(DD * DHID + 255) / 256, 256, 0, stream>>>(W1, W1T, DD, DHID);
  transpose_bf16_k<<<(DHID * DD + 255) / 256, 256, 0, stream>>>(W2, W2T, DHID, DD);
  concat_bias_k<<<6, 256, 0, stream>>>(bq, bk, bv, bsk, bqkvs);

  int e4 = E * DD / 4;
  f32_to_bf16_k<<<(e4 + 255) / 256, 256, 0, stream>>>(ea, eabf, e4);

  dim3 gqkvs((N + BM - 1) / BM, 1536 / BN);
  gemm_k<M_QKVS><<<gqkvs, 256, 0, stream>>>(hbuf, WqkvsT, bqkvs, nullptr, qkv, skip, N, DD, 1536);

  dim3 ge((E + BM - 1) / BM, DD / BN);
  gemm_k<M_BF16><<<ge, 256, 0, stream>>>(eabf, WeT, nullptr, nullptr, ebuf, nullptr, E, DD, DD);

  hist_k<<<(E + 255) / 256, 256, 0, stream>>>(ei, deg, E);
  scan_k<<<1, 1024, 0, stream>>>(deg, row_start, cursor, N);
  scatter_k<<<(E + 255) / 256, 256, 0, stream>>>(ei, cursor, csr_src, csr_eid, E);

  attn_k<<<(N * 64 + 255) / 256, 256, 0, stream>>>(qkv, ebuf, row_start, csr_src, csr_eid, agg, N);

  add3_k<<<(t4 + 255) / 256, 256, 0, stream>>>(x, agg, skip, x1, t4);

  bn_stats_k<<<sgrid, DD, 0, stream>>>(x1, bnsum + 2 * DD, bnsum + 3 * DD, N, rpb);
  bn_finalize_k<<<2, 256, 0, stream>>>(bnsum + 2 * DD, bnsum + 3 * DD, g2, b2, a2, c2, N);
  norm_to_bf16_k<<<(t4 + 255) / 256, 256, 0, stream>>>(x1, a2, c2, hbuf, t4);

  dim3 gm1((N + BM - 1) / BM, DHID / BN);
  gemm_k<M_GELU><<<gm1, 256, 0, stream>>>(hbuf, W1T, bm1, nullptr, hid, nullptr, N, DD, DHID);

  dim3 gm2((N + BM - 1) / BM, DD / BN);
  gemm_k<M_RES><<<gm2, 256, 0, stream>>>(hid, W2T, bm2, x1, (float*)d_out, nullptr, N, DHID, DD);
}